// Round 9
// baseline (137.172 us; speedup 1.0000x reference)
//
#include <hip/hip_runtime.h>
#include <stdint.h>

#define HH 1024
#define WW 1024
#define NB 16
#define KTOP 512
#define NBINS 4096
#define CAP 8192
#define ROWS 16          // output rows per wave-chunk

typedef unsigned long long u64;
typedef unsigned int u32;

__device__ __forceinline__ u32 fmap(float v) {
    u32 u = __float_as_uint(v);
    return (u & 0x80000000u) ? ~u : (u | 0x80000000u);
}
// contraction-proof scalar ops: guarantee bit-identical trees across kernels
__device__ __forceinline__ float fadd(float a, float b){ return __fadd_rn(a,b); }
__device__ __forceinline__ float fsub(float a, float b){ return __fsub_rn(a,b); }
__device__ __forceinline__ float fmul(float a, float b){ return __fmul_rn(a,b); }
__device__ __forceinline__ float add3(float a, float b, float c){ return fadd(fadd(a,b),c); }
// channel mean: IEEE division by 3 — matches rounds 1-5/7-8 validated tree
__device__ __forceinline__ float mean3(float a, float b, float c){
    return __fdiv_rn(add3(a,b,c), 3.0f);
}

__device__ __forceinline__ float g9(float w00,float w01,float w02,
                                    float w10,float w11,float w12,
                                    float w20,float w21,float w22){
    float s = fadd(w00, fmul(2.0f,w01));
    s = fadd(s, w02);
    s = fadd(s, fmul(2.0f,w10));
    s = fadd(s, fmul(4.0f,w11));
    s = fadd(s, fmul(2.0f,w12));
    s = fadd(s, w20);
    s = fadd(s, fmul(2.0f,w21));
    s = fadd(s, w22);
    return fmul(s, 0.0625f);
}
__device__ __forceinline__ u32 respkey(float Sxx,float Syy,float Sxy,bool masked){
    float det = fsub(fmul(Sxx,Syy), fmul(Sxy,Sxy));
    float tr  = fadd(Sxx,Syy);
    float R   = fsub(det, fmul(fmul(0.04f,tr),tr));
    if (masked) R = 0.0f;
    return fmap(R);
}

__device__ __forceinline__ float4 vmean(float4 a, float4 b, float4 c){
    return make_float4(mean3(a.x,b.x,c.x), mean3(a.y,b.y,c.y),
                       mean3(a.z,b.z,c.z), mean3(a.w,b.w,c.w));
}
__device__ __forceinline__ float4 vadd3(float4 a, float4 b, float4 c){
    return make_float4(add3(a.x,b.x,c.x), add3(a.y,b.y,c.y),
                       add3(a.z,b.z,c.z), add3(a.w,b.w,c.w));
}

// ---------------------------------------------------------------------------
// Pass A v2: register-streaming Harris, 6-column product rows (no key-stage
// shuffles), trimmed halo state, __launch_bounds__(256,4) for 4 waves/SIMD.
// One wave = 256-px strip x 16 output rows. No LDS, no barriers.
// Writes per-(row,64px) granule max key only. Keys bit-identical to harris_px.
__global__ __launch_bounds__(256, 4) void harris_a(const float* __restrict__ x,
                                                   u32* __restrict__ gmax) {
    const int b     = blockIdx.y;
    const int task  = blockIdx.x * 4 + (threadIdx.x >> 6);
    const int lane  = threadIdx.x & 63;
    const int strip = task & 3;
    const int y0    = (task >> 2) * ROWS;
    const int sx    = strip * 256;
    const int cx    = sx + 4 * lane;
    const int hx    = (lane < 32) ? max(sx - 4, 0) : min(sx + 256, WW - 4);
    const bool lo32 = (lane < 32);
    const float* p0 = x + (size_t)b * 3 * HH * WW;
    const float* p1 = p0 + HH * WW;
    const float* p2 = p1 + HH * WW;

    float4 z4 = make_float4(0.f,0.f,0.f,0.f);
    float4 m0=z4, m1=z4, m2=z4, h0=z4, h1=z4, h2=z4;
    float hma0=0.f,hma1=0.f,hma2=0.f, hmb0=0.f,hmb1=0.f,hmb2=0.f;
    float he0=0.f,he1=0.f,he2=0.f;
    float PXX[3][6], PYY[3][6], PXY[3][6];
    #pragma unroll
    for (int r = 0; r < 3; ++r)
        #pragma unroll
        for (int i = 0; i < 6; ++i) { PXX[r][i]=0.f; PYY[r][i]=0.f; PXY[r][i]=0.f; }

    #pragma unroll
    for (int t = 0; t < ROWS + 4; ++t) {
        // roll mean/h state
        m0=m1; m1=m2; h0=h1; h1=h2;
        hma0=hma1; hma1=hma2; hmb0=hmb1; hmb1=hmb2;
        he0=he1; he1=he2;
        int ym = min(max(y0 - 2 + t, 0), HH - 1);
        size_t ro = (size_t)ym * WW;
        float4 a0 = *(const float4*)(p0 + ro + cx);
        float4 a1 = *(const float4*)(p1 + ro + cx);
        float4 a2 = *(const float4*)(p2 + ro + cx);
        m2 = vmean(a0, a1, a2);
        float4 b0 = *(const float4*)(p0 + ro + hx);
        float4 b1 = *(const float4*)(p1 + ro + hx);
        float4 b2 = *(const float4*)(p2 + ro + hx);
        // trimmed halo means: lanes<32 use cols sx-2 (=.z), sx-1 (=.w);
        // lanes>=32 use cols sx+256 (=.x), sx+257 (=.y)
        {
            float ca0 = lo32 ? b0.z : b0.x, ca1 = lo32 ? b1.z : b1.x, ca2 = lo32 ? b2.z : b2.x;
            float cb0 = lo32 ? b0.w : b0.y, cb1 = lo32 ? b1.w : b1.y, cb2 = lo32 ? b2.w : b2.y;
            hma2 = mean3(ca0, ca1, ca2);
            hmb2 = mean3(cb0, cb1, cb2);
        }
        // horizontal sums of this mean row (h[c] = m[c-1]+m[c]+m[c+1])
        {
            float upw = __shfl_up(m2.w, 1);
            float dnx = __shfl_down(m2.x, 1);
            float lm  = (lane == 0)  ? hmb2 : upw;   // m at col 4l-1
            float rm  = (lane == 63) ? hma2 : dnx;   // m at col 4l+4
            h2 = make_float4(add3(lm,   m2.x, m2.y),
                             add3(m2.x, m2.y, m2.z),
                             add3(m2.y, m2.z, m2.w),
                             add3(m2.z, m2.w, rm));
            he2 = lo32 ? add3(hma2, hmb2, m2.x) : add3(m2.w, hma2, hmb2);
        }

        if (t >= 2) {
            // roll product rows
            #pragma unroll
            for (int i = 0; i < 6; ++i) {
                PXX[0][i]=PXX[1][i]; PXX[1][i]=PXX[2][i];
                PYY[0][i]=PYY[1][i]; PYY[1][i]=PYY[2][i];
                PXY[0][i]=PXY[1][i]; PXY[1][i]=PXY[2][i];
            }
            float4 s = vadd3(m0, m1, m2);                 // vertical sums, own cols
            float sva = add3(hma0, hma1, hma2);           // vertical sum, halo col a
            float svb = add3(hmb0, hmb1, hmb2);           // vertical sum, halo col b
            // dx at cols 4l..4l+3 (dx[c] = s[c+1]-s[c-1])
            float upsw = __shfl_up(s.w, 1);
            float dnsx = __shfl_down(s.x, 1);
            float sm1 = (lane == 0)  ? svb : upsw;        // s at col 4l-1
            float sp4 = (lane == 63) ? sva : dnsx;        // s at col 4l+4
            float dx0 = fsub(s.y, sm1);
            float dx1 = fsub(s.z, s.x);
            float dx2 = fsub(s.w, s.y);
            float dx3 = fsub(sp4, s.z);
            float updx = __shfl_up(dx3, 1);
            float dndx = __shfl_down(dx0, 1);
            float dxm1 = (lane == 0)  ? fsub(s.x, sva) : updx;   // dx at col 4l-1
            float dxp4 = (lane == 63) ? fsub(svb, s.w) : dndx;   // dx at col 4l+4
            // dy at cols 4l..4l+3 (dy = h2-h0)
            float dy0 = fsub(h2.x, h0.x);
            float dy1 = fsub(h2.y, h0.y);
            float dy2 = fsub(h2.z, h0.z);
            float dy3 = fsub(h2.w, h0.w);
            float dye = fsub(he2, he0);
            float updy = __shfl_up(dy3, 1);
            float dndy = __shfl_down(dy0, 1);
            float dym1 = (lane == 0)  ? dye : updy;
            float dyp4 = (lane == 63) ? dye : dndy;
            float DX[6] = {dxm1, dx0, dx1, dx2, dx3, dxp4};
            float DY[6] = {dym1, dy0, dy1, dy2, dy3, dyp4};
            #pragma unroll
            for (int i = 0; i < 6; ++i) {
                PXX[2][i] = fmul(DX[i], DX[i]);
                PYY[2][i] = fmul(DY[i], DY[i]);
                PXY[2][i] = fmul(DX[i], DY[i]);
            }
        }
        if (t >= 4) {
            int y = y0 + t - 4;
            bool rowm = (y < 5) || (y > HH - 6);
            u32 k[4];
            #pragma unroll
            for (int j = 0; j < 4; ++j) {
                // local col j..j+2 = image cols (4l+j)-1 .. (4l+j)+1
                float Sxx = g9(PXX[0][j],PXX[0][j+1],PXX[0][j+2],
                               PXX[1][j],PXX[1][j+1],PXX[1][j+2],
                               PXX[2][j],PXX[2][j+1],PXX[2][j+2]);
                float Syy = g9(PYY[0][j],PYY[0][j+1],PYY[0][j+2],
                               PYY[1][j],PYY[1][j+1],PYY[1][j+2],
                               PYY[2][j],PYY[2][j+1],PYY[2][j+2]);
                float Sxy = g9(PXY[0][j],PXY[0][j+1],PXY[0][j+2],
                               PXY[1][j],PXY[1][j+1],PXY[1][j+2],
                               PXY[2][j],PXY[2][j+1],PXY[2][j+2]);
                int gx = cx + j;
                bool mk = rowm || (gx < 5) || (gx > WW - 6);
                k[j] = respkey(Sxx, Syy, Sxy, mk);
            }
            u32 km = max(max(k[0], k[1]), max(k[2], k[3]));
            #pragma unroll
            for (int off = 1; off < 16; off <<= 1)
                km = max(km, (u32)__shfl_xor((int)km, off));
            if ((lane & 15) == 0)
                gmax[((size_t)b << 14) | ((size_t)y << 4) | (u32)(strip * 4 + (lane >> 4))] = km;
        }
    }
}

// ---------------------------------------------------------------------------
// Pass B (per batch): bin 16K granule maxes, pick largest bin with
// granule-suffix >= KTOP (sound cutoff), compact qualifying granule ids.
// Also zeroes the batch's padded candidate counter (replaces the memset).
__global__ __launch_bounds__(512) void select_b(const u32* __restrict__ gmax,
                                                u32* __restrict__ glist,
                                                u32* __restrict__ gcount,
                                                u32* __restrict__ cutb,
                                                u32* __restrict__ cnt) {
    __shared__ u32 hist[NBINS];
    __shared__ u32 wsum[8];
    __shared__ u32 s_cut, s_n;
    const int b = blockIdx.x;
    const int tid = threadIdx.x;
    const u32* gm = gmax + ((size_t)b << 14);
    u32 val[32];
    #pragma unroll
    for (int j = 0; j < 8; ++j) {
        uint4 v = ((const uint4*)gm)[tid + j * 512];
        val[j*4+0]=v.x; val[j*4+1]=v.y; val[j*4+2]=v.z; val[j*4+3]=v.w;
    }
    for (int i = tid; i < NBINS; i += 512) hist[i] = 0u;
    if (tid == 0) { s_n = 0u; cnt[b * 16] = 0u; }
    __syncthreads();
    #pragma unroll
    for (int j = 0; j < 32; ++j) atomicAdd(&hist[val[j] >> 20], 1u);
    __syncthreads();
    u32 lv[8], ls = 0;
    #pragma unroll
    for (int i = 0; i < 8; ++i) { lv[i] = hist[tid*8+i]; ls += lv[i]; }
    const int lane = tid & 63, w = tid >> 6;
    u32 v = ls;
    #pragma unroll
    for (int off = 1; off < 64; off <<= 1) {
        u32 t2 = (u32)__shfl_down((int)v, off);
        if (lane + off < 64) v += t2;
    }
    if (lane == 0) wsum[w] = v;
    __syncthreads();
    u32 excl = v - ls;
    #pragma unroll
    for (int i = 0; i < 8; ++i) if (i > w) excl += wsum[i];
    if (excl < KTOP && excl + ls >= KTOP) {       // exactly one thread
        u32 acc = excl;
        #pragma unroll
        for (int i = 7; i >= 0; --i) {
            acc += lv[i];
            if (acc >= KTOP) { s_cut = (u32)(tid*8 + i); break; }
        }
    }
    __syncthreads();
    const u32 cut = s_cut;
    u32* gl = glist + ((size_t)b << 14);
    #pragma unroll
    for (int j = 0; j < 8; ++j)
        #pragma unroll
        for (int kk = 0; kk < 4; ++kk) {
            u32 gv = val[j*4+kk];
            if ((gv >> 20) >= cut) {
                u32 q = atomicAdd(&s_n, 1u);
                gl[q] = (u32)(j*2048 + 4*tid + kk);
            }
        }
    __syncthreads();
    if (tid == 0) { gcount[b] = s_n; cutb[b] = cut; }
}

// ---------------------------------------------------------------------------
// Exact per-pixel recompute: identical _rn expression trees as harris_a.
__device__ __forceinline__ u32 harris_px(const float* __restrict__ p0,
                                         const float* __restrict__ p1,
                                         const float* __restrict__ p2,
                                         int gy, int gx) {
    if (gy < 5 || gy > HH - 6 || gx < 5 || gx > WW - 6) return 0x80000000u;
    float m[5][5];
    #pragma unroll
    for (int r = 0; r < 5; ++r)
        #pragma unroll
        for (int c = 0; c < 5; ++c) {
            size_t o = (size_t)(gy - 2 + r) * WW + (gx - 2 + c);
            m[r][c] = mean3(p0[o], p1[o], p2[o]);
        }
    float pxx[3][3], pyy[3][3], pxy[3][3];
    #pragma unroll
    for (int pr = 0; pr < 3; ++pr) {
        float s[5], ht[3], hb[3];
        #pragma unroll
        for (int c = 0; c < 5; ++c) s[c] = add3(m[pr][c], m[pr+1][c], m[pr+2][c]);
        #pragma unroll
        for (int c = 0; c < 3; ++c) {
            ht[c] = add3(m[pr][c],   m[pr][c+1],   m[pr][c+2]);
            hb[c] = add3(m[pr+2][c], m[pr+2][c+1], m[pr+2][c+2]);
        }
        #pragma unroll
        for (int pc = 0; pc < 3; ++pc) {
            float dx = fsub(s[pc+2], s[pc]);
            float dy = fsub(hb[pc], ht[pc]);
            pxx[pr][pc] = fmul(dx, dx);
            pyy[pr][pc] = fmul(dy, dy);
            pxy[pr][pc] = fmul(dx, dy);
        }
    }
    float Sxx = g9(pxx[0][0],pxx[0][1],pxx[0][2],pxx[1][0],pxx[1][1],pxx[1][2],pxx[2][0],pxx[2][1],pxx[2][2]);
    float Syy = g9(pyy[0][0],pyy[0][1],pyy[0][2],pyy[1][0],pyy[1][1],pyy[1][2],pyy[2][0],pyy[2][1],pyy[2][2]);
    float Sxy = g9(pxy[0][0],pxy[0][1],pxy[0][2],pxy[1][0],pxy[1][1],pxy[1][2],pxy[2][0],pxy[2][1],pxy[2][2]);
    return respkey(Sxx, Syy, Sxy, false);
}

// Pass C: recompute surviving granules; hits staged in block LDS (LDS atomics),
// ONE global atomicAdd per block on a per-batch padded counter.
__global__ __launch_bounds__(256) void refine_c(const float* __restrict__ x,
                                                const u32* __restrict__ glist,
                                                const u32* __restrict__ gcount,
                                                const u32* __restrict__ cutb,
                                                u32* __restrict__ cnt,
                                                u64* __restrict__ cand) {
    __shared__ u64 sbuf[CAP];       // 64 KB staging
    __shared__ u32 s_n, s_base;
    const int b = blockIdx.y;
    const u32 gc  = gcount[b];
    const u32 cut = cutb[b];
    const int tid = threadIdx.x;
    const int wv = tid >> 6, lane = tid & 63;
    if (tid == 0) s_n = 0u;
    __syncthreads();

    const u32 per = (gc + 31) >> 5;              // 32 blocks in x, contiguous chunks
    const u32 i0  = blockIdx.x * per;
    const u32 i1  = min(i0 + per, gc);
    const float* p0 = x + (size_t)b * 3 * HH * WW;
    const float* p1 = p0 + HH * WW;
    const float* p2 = p1 + HH * WW;
    const u32* gl = glist + ((size_t)b << 14);

    for (u32 i = i0 + wv; i < i1; i += 4) {
        u32 gid = gl[i];
        int gy = (int)(gid >> 4);
        int gx = (int)((gid & 15u) << 6) + lane;
        u32 key = harris_px(p0, p1, p2, gy, gx);
        bool pred = (key >> 20) >= cut;
        u64 mball = __ballot(pred);
        if (mball) {
            int first = __ffsll((unsigned long long)mball) - 1;
            u32 base = 0;
            if (lane == first) base = atomicAdd(&s_n, (u32)__popcll(mball));
            base = __shfl(base, first);
            if (pred) {
                u32 q = base + (u32)__popcll(mball & ((1ull << lane) - 1));
                if (q < CAP) sbuf[q] = ((u64)key << 32) | (u32)~((u32)(gy << 10) | (u32)gx);
            }
        }
    }
    __syncthreads();
    u32 n = min(s_n, (u32)CAP);
    if (tid == 0) s_base = atomicAdd(&cnt[b * 16], n);   // padded: 1 counter / 64B line
    __syncthreads();
    u32 gb = s_base;
    u64* cb = cand + (size_t)b * CAP;
    for (u32 j = tid; j < n; j += 256) {
        u32 q = gb + j;
        if (q < CAP) cb[q] = sbuf[j];
    }
}

// ---------------------------------------------------------------------------
// Pass D: per-batch bitonic sort + coords.
__global__ __launch_bounds__(1024) void sort_d(const u32* __restrict__ cnt,
                                               const u64* __restrict__ cand,
                                               float* __restrict__ out) {
    __shared__ u64 s[CAP];
    const int b = blockIdx.x;
    u32 n = cnt[b * 16];
    if (n > CAP) n = CAP;
    u32 P = 512;
    while (P < n) P <<= 1;
    for (u32 i = threadIdx.x; i < P; i += 1024)
        s[i] = (i < n) ? cand[(size_t)b * CAP + i] : 0ULL;
    __syncthreads();
    for (u32 size = 2; size <= P; size <<= 1) {
        for (u32 stride = size >> 1; stride > 0; stride >>= 1) {
            for (u32 t = threadIdx.x; t < (P >> 1); t += 1024) {
                u32 i = 2 * t - (t & (stride - 1));
                u32 j = i + stride;
                u64 a = s[i], c = s[j];
                bool desc = ((i & size) == 0);
                if (desc ? (a < c) : (a > c)) { s[i] = c; s[j] = a; }
            }
            __syncthreads();
        }
    }
    if (threadIdx.x < KTOP) {
        u64 k = s[threadIdx.x];
        u32 idx = ~(u32)k;
        u32 row = idx >> 10, col = idx & 1023;
        float rf = ((float)row * (1.0f / 1024.0f) - 0.5f) * 2.0f;
        float cf = ((float)col * (1.0f / 1024.0f) - 0.5f) * 2.0f;
        rf = fminf(fmaxf(rf, -1.0f), 1.0f);
        cf = fminf(fmaxf(cf, -1.0f), 1.0f);
        float* o = out + ((size_t)b * KTOP + threadIdx.x) * 2;
        o[0] = rf;
        o[1] = cf;
    }
}

extern "C" void kernel_launch(void* const* d_in, const int* in_sizes, int n_in,
                              void* d_out, int out_size, void* d_ws, size_t ws_size,
                              hipStream_t stream) {
    const float* x = (const float*)d_in[0];
    float* out = (float*)d_out;
    char* ws = (char*)d_ws;

    // ws layout (bytes):
    //   [0, 1MB)       gmax   u32[16*16384]
    //   [1MB, 2MB)     glist  u32[16*16384]
    //   @2MB           gcount u32[16]
    //   @2MB+64        cutb   u32[16]
    //   @2MB+128       cnt    u32[16*16]   (padded: one counter per 64B line)
    //   @2MB+2048      cand   u64[16*8192] (1MB)
    u32* gmax   = (u32*)ws;
    u32* glist  = (u32*)(ws + (1u << 20));
    u32* gcount = (u32*)(ws + (2u << 20));
    u32* cutb   = (u32*)(ws + (2u << 20) + 64);
    u32* cnt    = (u32*)(ws + (2u << 20) + 128);
    u64* cand   = (u64*)(ws + (2u << 20) + 2048);

    hipLaunchKernelGGL(harris_a, dim3(64, NB), dim3(256), 0, stream, x, gmax);
    hipLaunchKernelGGL(select_b, dim3(NB), dim3(512), 0, stream, gmax, glist, gcount, cutb, cnt);
    hipLaunchKernelGGL(refine_c, dim3(32, NB), dim3(256), 0, stream, x, glist, gcount, cutb, cnt, cand);
    hipLaunchKernelGGL(sort_d, dim3(NB), dim3(1024), 0, stream, cnt, cand, out);
}

// Round 10
// 113.861 us; speedup vs baseline: 1.2047x; 1.2047x over previous
//
#include <hip/hip_runtime.h>
#include <stdint.h>

#define HH 1024
#define WW 1024
#define NB 16
#define KTOP 512
#define NBINS 4096
#define CAP 8192
#define ROWS 16          // output rows per wave-chunk

typedef unsigned long long u64;
typedef unsigned int u32;

__device__ __forceinline__ u32 fmap(float v) {
    u32 u = __float_as_uint(v);
    return (u & 0x80000000u) ? ~u : (u | 0x80000000u);
}
// contraction-proof scalar ops: guarantee bit-identical trees across kernels
__device__ __forceinline__ float fadd(float a, float b){ return __fadd_rn(a,b); }
__device__ __forceinline__ float fsub(float a, float b){ return __fsub_rn(a,b); }
__device__ __forceinline__ float fmul(float a, float b){ return __fmul_rn(a,b); }
__device__ __forceinline__ float add3(float a, float b, float c){ return fadd(fadd(a,b),c); }
// channel mean: IEEE division by 3 — matches rounds 1-5/7-8 validated tree
__device__ __forceinline__ float mean3(float a, float b, float c){
    return __fdiv_rn(add3(a,b,c), 3.0f);
}

__device__ __forceinline__ float g9(float w00,float w01,float w02,
                                    float w10,float w11,float w12,
                                    float w20,float w21,float w22){
    float s = fadd(w00, fmul(2.0f,w01));
    s = fadd(s, w02);
    s = fadd(s, fmul(2.0f,w10));
    s = fadd(s, fmul(4.0f,w11));
    s = fadd(s, fmul(2.0f,w12));
    s = fadd(s, w20);
    s = fadd(s, fmul(2.0f,w21));
    s = fadd(s, w22);
    return fmul(s, 0.0625f);
}
__device__ __forceinline__ u32 respkey(float Sxx,float Syy,float Sxy,bool masked){
    float det = fsub(fmul(Sxx,Syy), fmul(Sxy,Sxy));
    float tr  = fadd(Sxx,Syy);
    float R   = fsub(det, fmul(fmul(0.04f,tr),tr));
    if (masked) R = 0.0f;
    return fmap(R);
}

__device__ __forceinline__ float4 vmean(float4 a, float4 b, float4 c){
    return make_float4(mean3(a.x,b.x,c.x), mean3(a.y,b.y,c.y),
                       mean3(a.z,b.z,c.z), mean3(a.w,b.w,c.w));
}
__device__ __forceinline__ float4 vadd3(float4 a, float4 b, float4 c){
    return make_float4(add3(a.x,b.x,c.x), add3(a.y,b.y,c.y),
                       add3(a.z,b.z,c.z), add3(a.w,b.w,c.w));
}

// ---------------------------------------------------------------------------
// Pass A v3: register-streaming Harris, 6-column product rows (no key-stage
// shuffles), trimmed halo state. __launch_bounds__(256,2): VGPR budget 256
// (round 9's (256,4) forced 64 VGPR -> 105 MB scratch spill, regression).
// One wave = 256-px strip x 16 output rows. No LDS, no barriers.
// Writes per-(row,64px) granule max key only. Keys bit-identical to harris_px.
__global__ __launch_bounds__(256, 2) void harris_a(const float* __restrict__ x,
                                                   u32* __restrict__ gmax) {
    const int b     = blockIdx.y;
    const int task  = blockIdx.x * 4 + (threadIdx.x >> 6);
    const int lane  = threadIdx.x & 63;
    const int strip = task & 3;
    const int y0    = (task >> 2) * ROWS;
    const int sx    = strip * 256;
    const int cx    = sx + 4 * lane;
    const int hx    = (lane < 32) ? max(sx - 4, 0) : min(sx + 256, WW - 4);
    const bool lo32 = (lane < 32);
    const float* p0 = x + (size_t)b * 3 * HH * WW;
    const float* p1 = p0 + HH * WW;
    const float* p2 = p1 + HH * WW;

    float4 z4 = make_float4(0.f,0.f,0.f,0.f);
    float4 m0=z4, m1=z4, m2=z4, h0=z4, h1=z4, h2=z4;
    float hma0=0.f,hma1=0.f,hma2=0.f, hmb0=0.f,hmb1=0.f,hmb2=0.f;
    float he0=0.f,he1=0.f,he2=0.f;
    float PXX[3][6], PYY[3][6], PXY[3][6];
    #pragma unroll
    for (int r = 0; r < 3; ++r)
        #pragma unroll
        for (int i = 0; i < 6; ++i) { PXX[r][i]=0.f; PYY[r][i]=0.f; PXY[r][i]=0.f; }

    #pragma unroll
    for (int t = 0; t < ROWS + 4; ++t) {
        // roll mean/h state
        m0=m1; m1=m2; h0=h1; h1=h2;
        hma0=hma1; hma1=hma2; hmb0=hmb1; hmb1=hmb2;
        he0=he1; he1=he2;
        int ym = min(max(y0 - 2 + t, 0), HH - 1);
        size_t ro = (size_t)ym * WW;
        float4 a0 = *(const float4*)(p0 + ro + cx);
        float4 a1 = *(const float4*)(p1 + ro + cx);
        float4 a2 = *(const float4*)(p2 + ro + cx);
        m2 = vmean(a0, a1, a2);
        float4 b0 = *(const float4*)(p0 + ro + hx);
        float4 b1 = *(const float4*)(p1 + ro + hx);
        float4 b2 = *(const float4*)(p2 + ro + hx);
        // trimmed halo means: lanes<32 use cols sx-2 (=.z), sx-1 (=.w);
        // lanes>=32 use cols sx+256 (=.x), sx+257 (=.y)
        {
            float ca0 = lo32 ? b0.z : b0.x, ca1 = lo32 ? b1.z : b1.x, ca2 = lo32 ? b2.z : b2.x;
            float cb0 = lo32 ? b0.w : b0.y, cb1 = lo32 ? b1.w : b1.y, cb2 = lo32 ? b2.w : b2.y;
            hma2 = mean3(ca0, ca1, ca2);
            hmb2 = mean3(cb0, cb1, cb2);
        }
        // horizontal sums of this mean row (h[c] = m[c-1]+m[c]+m[c+1])
        {
            float upw = __shfl_up(m2.w, 1);
            float dnx = __shfl_down(m2.x, 1);
            float lm  = (lane == 0)  ? hmb2 : upw;   // m at col 4l-1
            float rm  = (lane == 63) ? hma2 : dnx;   // m at col 4l+4
            h2 = make_float4(add3(lm,   m2.x, m2.y),
                             add3(m2.x, m2.y, m2.z),
                             add3(m2.y, m2.z, m2.w),
                             add3(m2.z, m2.w, rm));
            he2 = lo32 ? add3(hma2, hmb2, m2.x) : add3(m2.w, hma2, hmb2);
        }

        if (t >= 2) {
            // roll product rows
            #pragma unroll
            for (int i = 0; i < 6; ++i) {
                PXX[0][i]=PXX[1][i]; PXX[1][i]=PXX[2][i];
                PYY[0][i]=PYY[1][i]; PYY[1][i]=PYY[2][i];
                PXY[0][i]=PXY[1][i]; PXY[1][i]=PXY[2][i];
            }
            float4 s = vadd3(m0, m1, m2);                 // vertical sums, own cols
            float sva = add3(hma0, hma1, hma2);           // vertical sum, halo col a
            float svb = add3(hmb0, hmb1, hmb2);           // vertical sum, halo col b
            // dx at cols 4l..4l+3 (dx[c] = s[c+1]-s[c-1])
            float upsw = __shfl_up(s.w, 1);
            float dnsx = __shfl_down(s.x, 1);
            float sm1 = (lane == 0)  ? svb : upsw;        // s at col 4l-1
            float sp4 = (lane == 63) ? sva : dnsx;        // s at col 4l+4
            float dx0 = fsub(s.y, sm1);
            float dx1 = fsub(s.z, s.x);
            float dx2 = fsub(s.w, s.y);
            float dx3 = fsub(sp4, s.z);
            float updx = __shfl_up(dx3, 1);
            float dndx = __shfl_down(dx0, 1);
            float dxm1 = (lane == 0)  ? fsub(s.x, sva) : updx;   // dx at col 4l-1
            float dxp4 = (lane == 63) ? fsub(svb, s.w) : dndx;   // dx at col 4l+4
            // dy at cols 4l..4l+3 (dy = h2-h0)
            float dy0 = fsub(h2.x, h0.x);
            float dy1 = fsub(h2.y, h0.y);
            float dy2 = fsub(h2.z, h0.z);
            float dy3 = fsub(h2.w, h0.w);
            float dye = fsub(he2, he0);
            float updy = __shfl_up(dy3, 1);
            float dndy = __shfl_down(dy0, 1);
            float dym1 = (lane == 0)  ? dye : updy;
            float dyp4 = (lane == 63) ? dye : dndy;
            float DX[6] = {dxm1, dx0, dx1, dx2, dx3, dxp4};
            float DY[6] = {dym1, dy0, dy1, dy2, dy3, dyp4};
            #pragma unroll
            for (int i = 0; i < 6; ++i) {
                PXX[2][i] = fmul(DX[i], DX[i]);
                PYY[2][i] = fmul(DY[i], DY[i]);
                PXY[2][i] = fmul(DX[i], DY[i]);
            }
        }
        if (t >= 4) {
            int y = y0 + t - 4;
            bool rowm = (y < 5) || (y > HH - 6);
            u32 k[4];
            #pragma unroll
            for (int j = 0; j < 4; ++j) {
                // local col j..j+2 = image cols (4l+j)-1 .. (4l+j)+1
                float Sxx = g9(PXX[0][j],PXX[0][j+1],PXX[0][j+2],
                               PXX[1][j],PXX[1][j+1],PXX[1][j+2],
                               PXX[2][j],PXX[2][j+1],PXX[2][j+2]);
                float Syy = g9(PYY[0][j],PYY[0][j+1],PYY[0][j+2],
                               PYY[1][j],PYY[1][j+1],PYY[1][j+2],
                               PYY[2][j],PYY[2][j+1],PYY[2][j+2]);
                float Sxy = g9(PXY[0][j],PXY[0][j+1],PXY[0][j+2],
                               PXY[1][j],PXY[1][j+1],PXY[1][j+2],
                               PXY[2][j],PXY[2][j+1],PXY[2][j+2]);
                int gx = cx + j;
                bool mk = rowm || (gx < 5) || (gx > WW - 6);
                k[j] = respkey(Sxx, Syy, Sxy, mk);
            }
            u32 km = max(max(k[0], k[1]), max(k[2], k[3]));
            #pragma unroll
            for (int off = 1; off < 16; off <<= 1)
                km = max(km, (u32)__shfl_xor((int)km, off));
            if ((lane & 15) == 0)
                gmax[((size_t)b << 14) | ((size_t)y << 4) | (u32)(strip * 4 + (lane >> 4))] = km;
        }
    }
}

// ---------------------------------------------------------------------------
// Pass B (per batch): bin 16K granule maxes, pick largest bin with
// granule-suffix >= KTOP (sound cutoff), compact qualifying granule ids.
// Also zeroes the batch's padded candidate counter (replaces the memset).
__global__ __launch_bounds__(512) void select_b(const u32* __restrict__ gmax,
                                                u32* __restrict__ glist,
                                                u32* __restrict__ gcount,
                                                u32* __restrict__ cutb,
                                                u32* __restrict__ cnt) {
    __shared__ u32 hist[NBINS];
    __shared__ u32 wsum[8];
    __shared__ u32 s_cut, s_n;
    const int b = blockIdx.x;
    const int tid = threadIdx.x;
    const u32* gm = gmax + ((size_t)b << 14);
    u32 val[32];
    #pragma unroll
    for (int j = 0; j < 8; ++j) {
        uint4 v = ((const uint4*)gm)[tid + j * 512];
        val[j*4+0]=v.x; val[j*4+1]=v.y; val[j*4+2]=v.z; val[j*4+3]=v.w;
    }
    for (int i = tid; i < NBINS; i += 512) hist[i] = 0u;
    if (tid == 0) { s_n = 0u; cnt[b * 16] = 0u; }
    __syncthreads();
    #pragma unroll
    for (int j = 0; j < 32; ++j) atomicAdd(&hist[val[j] >> 20], 1u);
    __syncthreads();
    u32 lv[8], ls = 0;
    #pragma unroll
    for (int i = 0; i < 8; ++i) { lv[i] = hist[tid*8+i]; ls += lv[i]; }
    const int lane = tid & 63, w = tid >> 6;
    u32 v = ls;
    #pragma unroll
    for (int off = 1; off < 64; off <<= 1) {
        u32 t2 = (u32)__shfl_down((int)v, off);
        if (lane + off < 64) v += t2;
    }
    if (lane == 0) wsum[w] = v;
    __syncthreads();
    u32 excl = v - ls;
    #pragma unroll
    for (int i = 0; i < 8; ++i) if (i > w) excl += wsum[i];
    if (excl < KTOP && excl + ls >= KTOP) {       // exactly one thread
        u32 acc = excl;
        #pragma unroll
        for (int i = 7; i >= 0; --i) {
            acc += lv[i];
            if (acc >= KTOP) { s_cut = (u32)(tid*8 + i); break; }
        }
    }
    __syncthreads();
    const u32 cut = s_cut;
    u32* gl = glist + ((size_t)b << 14);
    #pragma unroll
    for (int j = 0; j < 8; ++j)
        #pragma unroll
        for (int kk = 0; kk < 4; ++kk) {
            u32 gv = val[j*4+kk];
            if ((gv >> 20) >= cut) {
                u32 q = atomicAdd(&s_n, 1u);
                gl[q] = (u32)(j*2048 + 4*tid + kk);
            }
        }
    __syncthreads();
    if (tid == 0) { gcount[b] = s_n; cutb[b] = cut; }
}

// ---------------------------------------------------------------------------
// Exact per-pixel recompute: identical _rn expression trees as harris_a.
__device__ __forceinline__ u32 harris_px(const float* __restrict__ p0,
                                         const float* __restrict__ p1,
                                         const float* __restrict__ p2,
                                         int gy, int gx) {
    if (gy < 5 || gy > HH - 6 || gx < 5 || gx > WW - 6) return 0x80000000u;
    float m[5][5];
    #pragma unroll
    for (int r = 0; r < 5; ++r)
        #pragma unroll
        for (int c = 0; c < 5; ++c) {
            size_t o = (size_t)(gy - 2 + r) * WW + (gx - 2 + c);
            m[r][c] = mean3(p0[o], p1[o], p2[o]);
        }
    float pxx[3][3], pyy[3][3], pxy[3][3];
    #pragma unroll
    for (int pr = 0; pr < 3; ++pr) {
        float s[5], ht[3], hb[3];
        #pragma unroll
        for (int c = 0; c < 5; ++c) s[c] = add3(m[pr][c], m[pr+1][c], m[pr+2][c]);
        #pragma unroll
        for (int c = 0; c < 3; ++c) {
            ht[c] = add3(m[pr][c],   m[pr][c+1],   m[pr][c+2]);
            hb[c] = add3(m[pr+2][c], m[pr+2][c+1], m[pr+2][c+2]);
        }
        #pragma unroll
        for (int pc = 0; pc < 3; ++pc) {
            float dx = fsub(s[pc+2], s[pc]);
            float dy = fsub(hb[pc], ht[pc]);
            pxx[pr][pc] = fmul(dx, dx);
            pyy[pr][pc] = fmul(dy, dy);
            pxy[pr][pc] = fmul(dx, dy);
        }
    }
    float Sxx = g9(pxx[0][0],pxx[0][1],pxx[0][2],pxx[1][0],pxx[1][1],pxx[1][2],pxx[2][0],pxx[2][1],pxx[2][2]);
    float Syy = g9(pyy[0][0],pyy[0][1],pyy[0][2],pyy[1][0],pyy[1][1],pyy[1][2],pyy[2][0],pyy[2][1],pyy[2][2]);
    float Sxy = g9(pxy[0][0],pxy[0][1],pxy[0][2],pxy[1][0],pxy[1][1],pxy[1][2],pxy[2][0],pxy[2][1],pxy[2][2]);
    return respkey(Sxx, Syy, Sxy, false);
}

// Pass C: recompute surviving granules; hits staged in block LDS (LDS atomics),
// ONE global atomicAdd per block on a per-batch padded counter.
__global__ __launch_bounds__(256) void refine_c(const float* __restrict__ x,
                                                const u32* __restrict__ glist,
                                                const u32* __restrict__ gcount,
                                                const u32* __restrict__ cutb,
                                                u32* __restrict__ cnt,
                                                u64* __restrict__ cand) {
    __shared__ u64 sbuf[CAP];       // 64 KB staging
    __shared__ u32 s_n, s_base;
    const int b = blockIdx.y;
    const u32 gc  = gcount[b];
    const u32 cut = cutb[b];
    const int tid = threadIdx.x;
    const int wv = tid >> 6, lane = tid & 63;
    if (tid == 0) s_n = 0u;
    __syncthreads();

    const u32 per = (gc + 31) >> 5;              // 32 blocks in x, contiguous chunks
    const u32 i0  = blockIdx.x * per;
    const u32 i1  = min(i0 + per, gc);
    const float* p0 = x + (size_t)b * 3 * HH * WW;
    const float* p1 = p0 + HH * WW;
    const float* p2 = p1 + HH * WW;
    const u32* gl = glist + ((size_t)b << 14);

    for (u32 i = i0 + wv; i < i1; i += 4) {
        u32 gid = gl[i];
        int gy = (int)(gid >> 4);
        int gx = (int)((gid & 15u) << 6) + lane;
        u32 key = harris_px(p0, p1, p2, gy, gx);
        bool pred = (key >> 20) >= cut;
        u64 mball = __ballot(pred);
        if (mball) {
            int first = __ffsll((unsigned long long)mball) - 1;
            u32 base = 0;
            if (lane == first) base = atomicAdd(&s_n, (u32)__popcll(mball));
            base = __shfl(base, first);
            if (pred) {
                u32 q = base + (u32)__popcll(mball & ((1ull << lane) - 1));
                if (q < CAP) sbuf[q] = ((u64)key << 32) | (u32)~((u32)(gy << 10) | (u32)gx);
            }
        }
    }
    __syncthreads();
    u32 n = min(s_n, (u32)CAP);
    if (tid == 0) s_base = atomicAdd(&cnt[b * 16], n);   // padded: 1 counter / 64B line
    __syncthreads();
    u32 gb = s_base;
    u64* cb = cand + (size_t)b * CAP;
    for (u32 j = tid; j < n; j += 256) {
        u32 q = gb + j;
        if (q < CAP) cb[q] = sbuf[j];
    }
}

// ---------------------------------------------------------------------------
// Pass D: per-batch bitonic sort + coords.
__global__ __launch_bounds__(1024) void sort_d(const u32* __restrict__ cnt,
                                               const u64* __restrict__ cand,
                                               float* __restrict__ out) {
    __shared__ u64 s[CAP];
    const int b = blockIdx.x;
    u32 n = cnt[b * 16];
    if (n > CAP) n = CAP;
    u32 P = 512;
    while (P < n) P <<= 1;
    for (u32 i = threadIdx.x; i < P; i += 1024)
        s[i] = (i < n) ? cand[(size_t)b * CAP + i] : 0ULL;
    __syncthreads();
    for (u32 size = 2; size <= P; size <<= 1) {
        for (u32 stride = size >> 1; stride > 0; stride >>= 1) {
            for (u32 t = threadIdx.x; t < (P >> 1); t += 1024) {
                u32 i = 2 * t - (t & (stride - 1));
                u32 j = i + stride;
                u64 a = s[i], c = s[j];
                bool desc = ((i & size) == 0);
                if (desc ? (a < c) : (a > c)) { s[i] = c; s[j] = a; }
            }
            __syncthreads();
        }
    }
    if (threadIdx.x < KTOP) {
        u64 k = s[threadIdx.x];
        u32 idx = ~(u32)k;
        u32 row = idx >> 10, col = idx & 1023;
        float rf = ((float)row * (1.0f / 1024.0f) - 0.5f) * 2.0f;
        float cf = ((float)col * (1.0f / 1024.0f) - 0.5f) * 2.0f;
        rf = fminf(fmaxf(rf, -1.0f), 1.0f);
        cf = fminf(fmaxf(cf, -1.0f), 1.0f);
        float* o = out + ((size_t)b * KTOP + threadIdx.x) * 2;
        o[0] = rf;
        o[1] = cf;
    }
}

extern "C" void kernel_launch(void* const* d_in, const int* in_sizes, int n_in,
                              void* d_out, int out_size, void* d_ws, size_t ws_size,
                              hipStream_t stream) {
    const float* x = (const float*)d_in[0];
    float* out = (float*)d_out;
    char* ws = (char*)d_ws;

    // ws layout (bytes):
    //   [0, 1MB)       gmax   u32[16*16384]
    //   [1MB, 2MB)     glist  u32[16*16384]
    //   @2MB           gcount u32[16]
    //   @2MB+64        cutb   u32[16]
    //   @2MB+128       cnt    u32[16*16]   (padded: one counter per 64B line)
    //   @2MB+2048      cand   u64[16*8192] (1MB)
    u32* gmax   = (u32*)ws;
    u32* glist  = (u32*)(ws + (1u << 20));
    u32* gcount = (u32*)(ws + (2u << 20));
    u32* cutb   = (u32*)(ws + (2u << 20) + 64);
    u32* cnt    = (u32*)(ws + (2u << 20) + 128);
    u64* cand   = (u64*)(ws + (2u << 20) + 2048);

    hipLaunchKernelGGL(harris_a, dim3(64, NB), dim3(256), 0, stream, x, gmax);
    hipLaunchKernelGGL(select_b, dim3(NB), dim3(512), 0, stream, gmax, glist, gcount, cutb, cnt);
    hipLaunchKernelGGL(refine_c, dim3(32, NB), dim3(256), 0, stream, x, glist, gcount, cutb, cnt, cand);
    hipLaunchKernelGGL(sort_d, dim3(NB), dim3(1024), 0, stream, cnt, cand, out);
}

// Round 11
// 102.573 us; speedup vs baseline: 1.3373x; 1.1101x over previous
//
#include <hip/hip_runtime.h>
#include <stdint.h>

#define HH 1024
#define WW 1024
#define NB 16
#define KTOP 512
#define NBINS 4096
#define CAP 8192
#define ROWS 16          // output rows per wave-chunk

typedef unsigned long long u64;
typedef unsigned int u32;

__device__ __forceinline__ u32 fmap(float v) {
    u32 u = __float_as_uint(v);
    return (u & 0x80000000u) ? ~u : (u | 0x80000000u);
}
// contraction-proof scalar ops: guarantee bit-identical trees across kernels
__device__ __forceinline__ float fadd(float a, float b){ return __fadd_rn(a,b); }
__device__ __forceinline__ float fsub(float a, float b){ return __fsub_rn(a,b); }
__device__ __forceinline__ float fmul(float a, float b){ return __fmul_rn(a,b); }
__device__ __forceinline__ float add3(float a, float b, float c){ return fadd(fadd(a,b),c); }
// channel mean: IEEE division by 3 — matches the validated tree
__device__ __forceinline__ float mean3(float a, float b, float c){
    return __fdiv_rn(add3(a,b,c), 3.0f);
}

__device__ __forceinline__ float g9(float w00,float w01,float w02,
                                    float w10,float w11,float w12,
                                    float w20,float w21,float w22){
    float s = fadd(w00, fmul(2.0f,w01));
    s = fadd(s, w02);
    s = fadd(s, fmul(2.0f,w10));
    s = fadd(s, fmul(4.0f,w11));
    s = fadd(s, fmul(2.0f,w12));
    s = fadd(s, w20);
    s = fadd(s, fmul(2.0f,w21));
    s = fadd(s, w22);
    return fmul(s, 0.0625f);
}
__device__ __forceinline__ u32 respkey(float Sxx,float Syy,float Sxy,bool masked){
    float det = fsub(fmul(Sxx,Syy), fmul(Sxy,Sxy));
    float tr  = fadd(Sxx,Syy);
    float R   = fsub(det, fmul(fmul(0.04f,tr),tr));
    if (masked) R = 0.0f;
    return fmap(R);
}

__device__ __forceinline__ float4 vmean(float4 a, float4 b, float4 c){
    return make_float4(mean3(a.x,b.x,c.x), mean3(a.y,b.y,c.y),
                       mean3(a.z,b.z,c.z), mean3(a.w,b.w,c.w));
}
__device__ __forceinline__ float4 vadd3(float4 a, float4 b, float4 c){
    return make_float4(add3(a.x,b.x,c.x), add3(a.y,b.y,c.y),
                       add3(a.z,b.z,c.z), add3(a.w,b.w,c.w));
}

// ---------------------------------------------------------------------------
// Pass A v4: register-streaming Harris with running Gaussian PREFIX
// ACCUMULATORS instead of a 3-row product delay line: 54 -> 24 persistent
// regs for the smoothing state, targeting the <=128-VGPR occupancy bracket.
// g9's left-to-right tree is split at its row boundaries (genuine subtrees),
// so keys remain bit-identical to harris_px.
// One wave = 256-px strip x 16 output rows. No LDS, no barriers.
__global__ __launch_bounds__(256, 2) void harris_a(const float* __restrict__ x,
                                                   u32* __restrict__ gmax) {
    const int b     = blockIdx.y;
    const int task  = blockIdx.x * 4 + (threadIdx.x >> 6);
    const int lane  = threadIdx.x & 63;
    const int strip = task & 3;
    const int y0    = (task >> 2) * ROWS;
    const int sx    = strip * 256;
    const int cx    = sx + 4 * lane;
    const int hx    = (lane < 32) ? max(sx - 4, 0) : min(sx + 256, WW - 4);
    const bool lo32 = (lane < 32);
    const float* p0 = x + (size_t)b * 3 * HH * WW;
    const float* p1 = p0 + HH * WW;
    const float* p2 = p1 + HH * WW;

    float4 z4 = make_float4(0.f,0.f,0.f,0.f);
    float4 m0=z4, m1=z4, m2=z4, h0=z4, h1=z4, h2=z4;
    float hma0=0.f,hma1=0.f,hma2=0.f, hmb0=0.f,hmb1=0.f,hmb2=0.f;
    float he0=0.f,he1=0.f,he2=0.f;
    // prefix accumulators: a1* = outputs having row0 only; a2* = rows 0+1.
    float a1xx[4], a1yy[4], a1xy[4], a2xx[4], a2yy[4], a2xy[4];
    #pragma unroll
    for (int j = 0; j < 4; ++j) {
        a1xx[j]=0.f; a1yy[j]=0.f; a1xy[j]=0.f;
        a2xx[j]=0.f; a2yy[j]=0.f; a2xy[j]=0.f;
    }

    #pragma unroll
    for (int t = 0; t < ROWS + 4; ++t) {
        // roll mean/h state
        m0=m1; m1=m2; h0=h1; h1=h2;
        hma0=hma1; hma1=hma2; hmb0=hmb1; hmb1=hmb2;
        he0=he1; he1=he2;
        int ym = min(max(y0 - 2 + t, 0), HH - 1);
        size_t ro = (size_t)ym * WW;
        float4 a0 = *(const float4*)(p0 + ro + cx);
        float4 a1v = *(const float4*)(p1 + ro + cx);
        float4 a2v = *(const float4*)(p2 + ro + cx);
        m2 = vmean(a0, a1v, a2v);
        float4 b0 = *(const float4*)(p0 + ro + hx);
        float4 b1 = *(const float4*)(p1 + ro + hx);
        float4 b2 = *(const float4*)(p2 + ro + hx);
        // trimmed halo means: lanes<32 use cols sx-2 (=.z), sx-1 (=.w);
        // lanes>=32 use cols sx+256 (=.x), sx+257 (=.y)
        {
            float ca0 = lo32 ? b0.z : b0.x, ca1 = lo32 ? b1.z : b1.x, ca2 = lo32 ? b2.z : b2.x;
            float cb0 = lo32 ? b0.w : b0.y, cb1 = lo32 ? b1.w : b1.y, cb2 = lo32 ? b2.w : b2.y;
            hma2 = mean3(ca0, ca1, ca2);
            hmb2 = mean3(cb0, cb1, cb2);
        }
        // horizontal sums of this mean row (h[c] = m[c-1]+m[c]+m[c+1])
        {
            float upw = __shfl_up(m2.w, 1);
            float dnx = __shfl_down(m2.x, 1);
            float lm  = (lane == 0)  ? hmb2 : upw;   // m at col 4l-1
            float rm  = (lane == 63) ? hma2 : dnx;   // m at col 4l+4
            h2 = make_float4(add3(lm,   m2.x, m2.y),
                             add3(m2.x, m2.y, m2.z),
                             add3(m2.y, m2.z, m2.w),
                             add3(m2.z, m2.w, rm));
            he2 = lo32 ? add3(hma2, hmb2, m2.x) : add3(m2.w, hma2, hmb2);
        }

        if (t >= 2) {
            // product row p = y0 + t - 3, 6 local cols (own 4 + one each side)
            float4 s = vadd3(m0, m1, m2);                 // vertical sums, own cols
            float sva = add3(hma0, hma1, hma2);           // vertical sum, halo col a
            float svb = add3(hmb0, hmb1, hmb2);           // vertical sum, halo col b
            float upsw = __shfl_up(s.w, 1);
            float dnsx = __shfl_down(s.x, 1);
            float sm1 = (lane == 0)  ? svb : upsw;        // s at col 4l-1
            float sp4 = (lane == 63) ? sva : dnsx;        // s at col 4l+4
            float dx0 = fsub(s.y, sm1);
            float dx1 = fsub(s.z, s.x);
            float dx2 = fsub(s.w, s.y);
            float dx3 = fsub(sp4, s.z);
            float updx = __shfl_up(dx3, 1);
            float dndx = __shfl_down(dx0, 1);
            float dxm1 = (lane == 0)  ? fsub(s.x, sva) : updx;   // dx at col 4l-1
            float dxp4 = (lane == 63) ? fsub(svb, s.w) : dndx;   // dx at col 4l+4
            float dy0 = fsub(h2.x, h0.x);
            float dy1 = fsub(h2.y, h0.y);
            float dy2 = fsub(h2.z, h0.z);
            float dy3 = fsub(h2.w, h0.w);
            float dye = fsub(he2, he0);
            float updy = __shfl_up(dy3, 1);
            float dndy = __shfl_down(dy0, 1);
            float dym1 = (lane == 0)  ? dye : updy;
            float dyp4 = (lane == 63) ? dye : dndy;
            float DX[6] = {dxm1, dx0, dx1, dx2, dx3, dxp4};
            float DY[6] = {dym1, dy0, dy1, dy2, dy3, dyp4};
            float pxx[6], pyy[6], pxy[6];
            #pragma unroll
            for (int i = 0; i < 6; ++i) {
                pxx[i] = fmul(DX[i], DX[i]);
                pyy[i] = fmul(DY[i], DY[i]);
                pxy[i] = fmul(DX[i], DY[i]);
            }

            if (t >= 4) {
                // finish output row y = p-1 = y0+t-4 (this row's products are its row2)
                int y = y0 + t - 4;
                bool rowm = (y < 5) || (y > HH - 6);
                u32 k[4];
                #pragma unroll
                for (int j = 0; j < 4; ++j) {
                    float Sxx = fmul(fadd(fadd(fadd(a2xx[j], pxx[j]),
                                    fmul(2.0f,pxx[j+1])), pxx[j+2]), 0.0625f);
                    float Syy = fmul(fadd(fadd(fadd(a2yy[j], pyy[j]),
                                    fmul(2.0f,pyy[j+1])), pyy[j+2]), 0.0625f);
                    float Sxy = fmul(fadd(fadd(fadd(a2xy[j], pxy[j]),
                                    fmul(2.0f,pxy[j+1])), pxy[j+2]), 0.0625f);
                    int gx = cx + j;
                    bool mk = rowm || (gx < 5) || (gx > WW - 6);
                    k[j] = respkey(Sxx, Syy, Sxy, mk);
                }
                u32 km = max(max(k[0], k[1]), max(k[2], k[3]));
                #pragma unroll
                for (int off = 1; off < 16; off <<= 1)
                    km = max(km, (u32)__shfl_xor((int)km, off));
                if ((lane & 15) == 0)
                    gmax[((size_t)b << 14) | ((size_t)y << 4) | (u32)(strip * 4 + (lane >> 4))] = km;
            }
            // advance accumulators: this row is row1 for output p, row0 for p+1
            #pragma unroll
            for (int j = 0; j < 4; ++j) {
                a2xx[j] = fadd(fadd(fadd(a1xx[j], fmul(2.0f,pxx[j])),
                               fmul(4.0f,pxx[j+1])), fmul(2.0f,pxx[j+2]));
                a2yy[j] = fadd(fadd(fadd(a1yy[j], fmul(2.0f,pyy[j])),
                               fmul(4.0f,pyy[j+1])), fmul(2.0f,pyy[j+2]));
                a2xy[j] = fadd(fadd(fadd(a1xy[j], fmul(2.0f,pxy[j])),
                               fmul(4.0f,pxy[j+1])), fmul(2.0f,pxy[j+2]));
                a1xx[j] = fadd(fadd(pxx[j], fmul(2.0f,pxx[j+1])), pxx[j+2]);
                a1yy[j] = fadd(fadd(pyy[j], fmul(2.0f,pyy[j+1])), pyy[j+2]);
                a1xy[j] = fadd(fadd(pxy[j], fmul(2.0f,pxy[j+1])), pxy[j+2]);
            }
        }
    }
}

// ---------------------------------------------------------------------------
// Pass B (per batch): bin 16K granule maxes, pick largest bin with
// granule-suffix >= KTOP (sound cutoff), compact qualifying granule ids.
// Also zeroes the batch's padded candidate counter.
__global__ __launch_bounds__(512) void select_b(const u32* __restrict__ gmax,
                                                u32* __restrict__ glist,
                                                u32* __restrict__ gcount,
                                                u32* __restrict__ cutb,
                                                u32* __restrict__ cnt) {
    __shared__ u32 hist[NBINS];
    __shared__ u32 wsum[8];
    __shared__ u32 s_cut, s_n;
    const int b = blockIdx.x;
    const int tid = threadIdx.x;
    const u32* gm = gmax + ((size_t)b << 14);
    u32 val[32];
    #pragma unroll
    for (int j = 0; j < 8; ++j) {
        uint4 v = ((const uint4*)gm)[tid + j * 512];
        val[j*4+0]=v.x; val[j*4+1]=v.y; val[j*4+2]=v.z; val[j*4+3]=v.w;
    }
    for (int i = tid; i < NBINS; i += 512) hist[i] = 0u;
    if (tid == 0) { s_n = 0u; cnt[b * 16] = 0u; }
    __syncthreads();
    #pragma unroll
    for (int j = 0; j < 32; ++j) atomicAdd(&hist[val[j] >> 20], 1u);
    __syncthreads();
    u32 lv[8], ls = 0;
    #pragma unroll
    for (int i = 0; i < 8; ++i) { lv[i] = hist[tid*8+i]; ls += lv[i]; }
    const int lane = tid & 63, w = tid >> 6;
    u32 v = ls;
    #pragma unroll
    for (int off = 1; off < 64; off <<= 1) {
        u32 t2 = (u32)__shfl_down((int)v, off);
        if (lane + off < 64) v += t2;
    }
    if (lane == 0) wsum[w] = v;
    __syncthreads();
    u32 excl = v - ls;
    #pragma unroll
    for (int i = 0; i < 8; ++i) if (i > w) excl += wsum[i];
    if (excl < KTOP && excl + ls >= KTOP) {       // exactly one thread
        u32 acc = excl;
        #pragma unroll
        for (int i = 7; i >= 0; --i) {
            acc += lv[i];
            if (acc >= KTOP) { s_cut = (u32)(tid*8 + i); break; }
        }
    }
    __syncthreads();
    const u32 cut = s_cut;
    u32* gl = glist + ((size_t)b << 14);
    #pragma unroll
    for (int j = 0; j < 8; ++j)
        #pragma unroll
        for (int kk = 0; kk < 4; ++kk) {
            u32 gv = val[j*4+kk];
            if ((gv >> 20) >= cut) {
                u32 q = atomicAdd(&s_n, 1u);
                gl[q] = (u32)(j*2048 + 4*tid + kk);
            }
        }
    __syncthreads();
    if (tid == 0) { gcount[b] = s_n; cutb[b] = cut; }
}

// ---------------------------------------------------------------------------
// Exact per-pixel recompute: identical _rn expression trees as harris_a.
__device__ __forceinline__ u32 harris_px(const float* __restrict__ p0,
                                         const float* __restrict__ p1,
                                         const float* __restrict__ p2,
                                         int gy, int gx) {
    if (gy < 5 || gy > HH - 6 || gx < 5 || gx > WW - 6) return 0x80000000u;
    float m[5][5];
    #pragma unroll
    for (int r = 0; r < 5; ++r)
        #pragma unroll
        for (int c = 0; c < 5; ++c) {
            size_t o = (size_t)(gy - 2 + r) * WW + (gx - 2 + c);
            m[r][c] = mean3(p0[o], p1[o], p2[o]);
        }
    float pxx[3][3], pyy[3][3], pxy[3][3];
    #pragma unroll
    for (int pr = 0; pr < 3; ++pr) {
        float s[5], ht[3], hb[3];
        #pragma unroll
        for (int c = 0; c < 5; ++c) s[c] = add3(m[pr][c], m[pr+1][c], m[pr+2][c]);
        #pragma unroll
        for (int c = 0; c < 3; ++c) {
            ht[c] = add3(m[pr][c],   m[pr][c+1],   m[pr][c+2]);
            hb[c] = add3(m[pr+2][c], m[pr+2][c+1], m[pr+2][c+2]);
        }
        #pragma unroll
        for (int pc = 0; pc < 3; ++pc) {
            float dx = fsub(s[pc+2], s[pc]);
            float dy = fsub(hb[pc], ht[pc]);
            pxx[pr][pc] = fmul(dx, dx);
            pyy[pr][pc] = fmul(dy, dy);
            pxy[pr][pc] = fmul(dx, dy);
        }
    }
    float Sxx = g9(pxx[0][0],pxx[0][1],pxx[0][2],pxx[1][0],pxx[1][1],pxx[1][2],pxx[2][0],pxx[2][1],pxx[2][2]);
    float Syy = g9(pyy[0][0],pyy[0][1],pyy[0][2],pyy[1][0],pyy[1][1],pyy[1][2],pyy[2][0],pyy[2][1],pyy[2][2]);
    float Sxy = g9(pxy[0][0],pxy[0][1],pxy[0][2],pxy[1][0],pxy[1][1],pxy[1][2],pxy[2][0],pxy[2][1],pxy[2][2]);
    return respkey(Sxx, Syy, Sxy, false);
}

// Pass C: recompute surviving granules; hits staged in block LDS (LDS atomics),
// ONE global atomicAdd per block on a per-batch padded counter.
__global__ __launch_bounds__(256) void refine_c(const float* __restrict__ x,
                                                const u32* __restrict__ glist,
                                                const u32* __restrict__ gcount,
                                                const u32* __restrict__ cutb,
                                                u32* __restrict__ cnt,
                                                u64* __restrict__ cand) {
    __shared__ u64 sbuf[CAP];       // 64 KB staging
    __shared__ u32 s_n, s_base;
    const int b = blockIdx.y;
    const u32 gc  = gcount[b];
    const u32 cut = cutb[b];
    const int tid = threadIdx.x;
    const int wv = tid >> 6, lane = tid & 63;
    if (tid == 0) s_n = 0u;
    __syncthreads();

    const u32 per = (gc + 31) >> 5;              // 32 blocks in x, contiguous chunks
    const u32 i0  = blockIdx.x * per;
    const u32 i1  = min(i0 + per, gc);
    const float* p0 = x + (size_t)b * 3 * HH * WW;
    const float* p1 = p0 + HH * WW;
    const float* p2 = p1 + HH * WW;
    const u32* gl = glist + ((size_t)b << 14);

    for (u32 i = i0 + wv; i < i1; i += 4) {
        u32 gid = gl[i];
        int gy = (int)(gid >> 4);
        int gx = (int)((gid & 15u) << 6) + lane;
        u32 key = harris_px(p0, p1, p2, gy, gx);
        bool pred = (key >> 20) >= cut;
        u64 mball = __ballot(pred);
        if (mball) {
            int first = __ffsll((unsigned long long)mball) - 1;
            u32 base = 0;
            if (lane == first) base = atomicAdd(&s_n, (u32)__popcll(mball));
            base = __shfl(base, first);
            if (pred) {
                u32 q = base + (u32)__popcll(mball & ((1ull << lane) - 1));
                if (q < CAP) sbuf[q] = ((u64)key << 32) | (u32)~((u32)(gy << 10) | (u32)gx);
            }
        }
    }
    __syncthreads();
    u32 n = min(s_n, (u32)CAP);
    if (tid == 0) s_base = atomicAdd(&cnt[b * 16], n);   // padded: 1 counter / 64B line
    __syncthreads();
    u32 gb = s_base;
    u64* cb = cand + (size_t)b * CAP;
    for (u32 j = tid; j < n; j += 256) {
        u32 q = gb + j;
        if (q < CAP) cb[q] = sbuf[j];
    }
}

// ---------------------------------------------------------------------------
// Pass D: per-batch bitonic sort + coords.
__global__ __launch_bounds__(1024) void sort_d(const u32* __restrict__ cnt,
                                               const u64* __restrict__ cand,
                                               float* __restrict__ out) {
    __shared__ u64 s[CAP];
    const int b = blockIdx.x;
    u32 n = cnt[b * 16];
    if (n > CAP) n = CAP;
    u32 P = 512;
    while (P < n) P <<= 1;
    for (u32 i = threadIdx.x; i < P; i += 1024)
        s[i] = (i < n) ? cand[(size_t)b * CAP + i] : 0ULL;
    __syncthreads();
    for (u32 size = 2; size <= P; size <<= 1) {
        for (u32 stride = size >> 1; stride > 0; stride >>= 1) {
            for (u32 t = threadIdx.x; t < (P >> 1); t += 1024) {
                u32 i = 2 * t - (t & (stride - 1));
                u32 j = i + stride;
                u64 a = s[i], c = s[j];
                bool desc = ((i & size) == 0);
                if (desc ? (a < c) : (a > c)) { s[i] = c; s[j] = a; }
            }
            __syncthreads();
        }
    }
    if (threadIdx.x < KTOP) {
        u64 k = s[threadIdx.x];
        u32 idx = ~(u32)k;
        u32 row = idx >> 10, col = idx & 1023;
        float rf = ((float)row * (1.0f / 1024.0f) - 0.5f) * 2.0f;
        float cf = ((float)col * (1.0f / 1024.0f) - 0.5f) * 2.0f;
        rf = fminf(fmaxf(rf, -1.0f), 1.0f);
        cf = fminf(fmaxf(cf, -1.0f), 1.0f);
        float* o = out + ((size_t)b * KTOP + threadIdx.x) * 2;
        o[0] = rf;
        o[1] = cf;
    }
}

extern "C" void kernel_launch(void* const* d_in, const int* in_sizes, int n_in,
                              void* d_out, int out_size, void* d_ws, size_t ws_size,
                              hipStream_t stream) {
    const float* x = (const float*)d_in[0];
    float* out = (float*)d_out;
    char* ws = (char*)d_ws;

    // ws layout (bytes):
    //   [0, 1MB)       gmax   u32[16*16384]
    //   [1MB, 2MB)     glist  u32[16*16384]
    //   @2MB           gcount u32[16]
    //   @2MB+64        cutb   u32[16]
    //   @2MB+128       cnt    u32[16*16]   (padded: one counter per 64B line)
    //   @2MB+2048      cand   u64[16*8192] (1MB)
    u32* gmax   = (u32*)ws;
    u32* glist  = (u32*)(ws + (1u << 20));
    u32* gcount = (u32*)(ws + (2u << 20));
    u32* cutb   = (u32*)(ws + (2u << 20) + 64);
    u32* cnt    = (u32*)(ws + (2u << 20) + 128);
    u64* cand   = (u64*)(ws + (2u << 20) + 2048);

    hipLaunchKernelGGL(harris_a, dim3(64, NB), dim3(256), 0, stream, x, gmax);
    hipLaunchKernelGGL(select_b, dim3(NB), dim3(512), 0, stream, gmax, glist, gcount, cutb, cnt);
    hipLaunchKernelGGL(refine_c, dim3(32, NB), dim3(256), 0, stream, x, glist, gcount, cutb, cnt, cand);
    hipLaunchKernelGGL(sort_d, dim3(NB), dim3(1024), 0, stream, cnt, cand, out);
}

// Round 12
// 102.072 us; speedup vs baseline: 1.3439x; 1.0049x over previous
//
#include <hip/hip_runtime.h>
#include <stdint.h>

#define HH 1024
#define WW 1024
#define NB 16
#define KTOP 512
#define NBINS 4096
#define CAP 8192
#define LCAP 4096        // refine per-block LDS staging entries (32 KB)
#define RGRID 64         // refine blocks per batch
#define ROWS 16          // output rows per wave-chunk

typedef unsigned long long u64;
typedef unsigned int u32;

__device__ __forceinline__ u32 fmap(float v) {
    u32 u = __float_as_uint(v);
    return (u & 0x80000000u) ? ~u : (u | 0x80000000u);
}
// contraction-proof scalar ops: guarantee bit-identical trees across kernels
__device__ __forceinline__ float fadd(float a, float b){ return __fadd_rn(a,b); }
__device__ __forceinline__ float fsub(float a, float b){ return __fsub_rn(a,b); }
__device__ __forceinline__ float fmul(float a, float b){ return __fmul_rn(a,b); }
__device__ __forceinline__ float add3(float a, float b, float c){ return fadd(fadd(a,b),c); }
// channel mean: IEEE division by 3 — matches the validated tree
__device__ __forceinline__ float mean3(float a, float b, float c){
    return __fdiv_rn(add3(a,b,c), 3.0f);
}

__device__ __forceinline__ float g9(float w00,float w01,float w02,
                                    float w10,float w11,float w12,
                                    float w20,float w21,float w22){
    float s = fadd(w00, fmul(2.0f,w01));
    s = fadd(s, w02);
    s = fadd(s, fmul(2.0f,w10));
    s = fadd(s, fmul(4.0f,w11));
    s = fadd(s, fmul(2.0f,w12));
    s = fadd(s, w20);
    s = fadd(s, fmul(2.0f,w21));
    s = fadd(s, w22);
    return fmul(s, 0.0625f);
}
__device__ __forceinline__ u32 respkey(float Sxx,float Syy,float Sxy,bool masked){
    float det = fsub(fmul(Sxx,Syy), fmul(Sxy,Sxy));
    float tr  = fadd(Sxx,Syy);
    float R   = fsub(det, fmul(fmul(0.04f,tr),tr));
    if (masked) R = 0.0f;
    return fmap(R);
}

__device__ __forceinline__ float4 vmean(float4 a, float4 b, float4 c){
    return make_float4(mean3(a.x,b.x,c.x), mean3(a.y,b.y,c.y),
                       mean3(a.z,b.z,c.z), mean3(a.w,b.w,c.w));
}
__device__ __forceinline__ float4 vadd3(float4 a, float4 b, float4 c){
    return make_float4(add3(a.x,b.x,c.x), add3(a.y,b.y,c.y),
                       add3(a.z,b.z,c.z), add3(a.w,b.w,c.w));
}

// ---------------------------------------------------------------------------
// Pass A v5: register-streaming Harris with prefix accumulators (v4) +
// XCD-aware (batch,y-chunk) swizzle so consecutive y-chunks (which share 4
// halo rows) land on the same XCD's L2. Bijective: transpose of 128x8.
// Keys bit-identical to harris_px.
__global__ __launch_bounds__(256, 2) void harris_a(const float* __restrict__ x,
                                                   u32* __restrict__ gmax) {
    const int lin   = blockIdx.y * 64 + blockIdx.x;   // [0,1024)
    const int xcd   = lin & 7, ridx = lin >> 3;
    const int nl    = xcd * 128 + ridx;               // bijective remap
    const int b     = nl >> 6;
    const int chunk = nl & 63;
    const int wid   = threadIdx.x >> 6;
    const int lane  = threadIdx.x & 63;
    const int strip = wid;
    const int y0    = chunk * ROWS;
    const int sx    = strip * 256;
    const int cx    = sx + 4 * lane;
    const int hx    = (lane < 32) ? max(sx - 4, 0) : min(sx + 256, WW - 4);
    const bool lo32 = (lane < 32);
    const float* p0 = x + (size_t)b * 3 * HH * WW;
    const float* p1 = p0 + HH * WW;
    const float* p2 = p1 + HH * WW;

    float4 z4 = make_float4(0.f,0.f,0.f,0.f);
    float4 m0=z4, m1=z4, m2=z4, h0=z4, h1=z4, h2=z4;
    float hma0=0.f,hma1=0.f,hma2=0.f, hmb0=0.f,hmb1=0.f,hmb2=0.f;
    float he0=0.f,he1=0.f,he2=0.f;
    float a1xx[4], a1yy[4], a1xy[4], a2xx[4], a2yy[4], a2xy[4];
    #pragma unroll
    for (int j = 0; j < 4; ++j) {
        a1xx[j]=0.f; a1yy[j]=0.f; a1xy[j]=0.f;
        a2xx[j]=0.f; a2yy[j]=0.f; a2xy[j]=0.f;
    }

    #pragma unroll
    for (int t = 0; t < ROWS + 4; ++t) {
        m0=m1; m1=m2; h0=h1; h1=h2;
        hma0=hma1; hma1=hma2; hmb0=hmb1; hmb1=hmb2;
        he0=he1; he1=he2;
        int ym = min(max(y0 - 2 + t, 0), HH - 1);
        size_t ro = (size_t)ym * WW;
        float4 a0 = *(const float4*)(p0 + ro + cx);
        float4 a1v = *(const float4*)(p1 + ro + cx);
        float4 a2v = *(const float4*)(p2 + ro + cx);
        m2 = vmean(a0, a1v, a2v);
        float4 b0 = *(const float4*)(p0 + ro + hx);
        float4 b1 = *(const float4*)(p1 + ro + hx);
        float4 b2 = *(const float4*)(p2 + ro + hx);
        {
            float ca0 = lo32 ? b0.z : b0.x, ca1 = lo32 ? b1.z : b1.x, ca2 = lo32 ? b2.z : b2.x;
            float cb0 = lo32 ? b0.w : b0.y, cb1 = lo32 ? b1.w : b1.y, cb2 = lo32 ? b2.w : b2.y;
            hma2 = mean3(ca0, ca1, ca2);
            hmb2 = mean3(cb0, cb1, cb2);
        }
        {
            float upw = __shfl_up(m2.w, 1);
            float dnx = __shfl_down(m2.x, 1);
            float lm  = (lane == 0)  ? hmb2 : upw;
            float rm  = (lane == 63) ? hma2 : dnx;
            h2 = make_float4(add3(lm,   m2.x, m2.y),
                             add3(m2.x, m2.y, m2.z),
                             add3(m2.y, m2.z, m2.w),
                             add3(m2.z, m2.w, rm));
            he2 = lo32 ? add3(hma2, hmb2, m2.x) : add3(m2.w, hma2, hmb2);
        }

        if (t >= 2) {
            float4 s = vadd3(m0, m1, m2);
            float sva = add3(hma0, hma1, hma2);
            float svb = add3(hmb0, hmb1, hmb2);
            float upsw = __shfl_up(s.w, 1);
            float dnsx = __shfl_down(s.x, 1);
            float sm1 = (lane == 0)  ? svb : upsw;
            float sp4 = (lane == 63) ? sva : dnsx;
            float dx0 = fsub(s.y, sm1);
            float dx1 = fsub(s.z, s.x);
            float dx2 = fsub(s.w, s.y);
            float dx3 = fsub(sp4, s.z);
            float updx = __shfl_up(dx3, 1);
            float dndx = __shfl_down(dx0, 1);
            float dxm1 = (lane == 0)  ? fsub(s.x, sva) : updx;
            float dxp4 = (lane == 63) ? fsub(svb, s.w) : dndx;
            float dy0 = fsub(h2.x, h0.x);
            float dy1 = fsub(h2.y, h0.y);
            float dy2 = fsub(h2.z, h0.z);
            float dy3 = fsub(h2.w, h0.w);
            float dye = fsub(he2, he0);
            float updy = __shfl_up(dy3, 1);
            float dndy = __shfl_down(dy0, 1);
            float dym1 = (lane == 0)  ? dye : updy;
            float dyp4 = (lane == 63) ? dye : dndy;
            float DX[6] = {dxm1, dx0, dx1, dx2, dx3, dxp4};
            float DY[6] = {dym1, dy0, dy1, dy2, dy3, dyp4};
            float pxx[6], pyy[6], pxy[6];
            #pragma unroll
            for (int i = 0; i < 6; ++i) {
                pxx[i] = fmul(DX[i], DX[i]);
                pyy[i] = fmul(DY[i], DY[i]);
                pxy[i] = fmul(DX[i], DY[i]);
            }

            if (t >= 4) {
                int y = y0 + t - 4;
                bool rowm = (y < 5) || (y > HH - 6);
                u32 k[4];
                #pragma unroll
                for (int j = 0; j < 4; ++j) {
                    float Sxx = fmul(fadd(fadd(fadd(a2xx[j], pxx[j]),
                                    fmul(2.0f,pxx[j+1])), pxx[j+2]), 0.0625f);
                    float Syy = fmul(fadd(fadd(fadd(a2yy[j], pyy[j]),
                                    fmul(2.0f,pyy[j+1])), pyy[j+2]), 0.0625f);
                    float Sxy = fmul(fadd(fadd(fadd(a2xy[j], pxy[j]),
                                    fmul(2.0f,pxy[j+1])), pxy[j+2]), 0.0625f);
                    int gx = cx + j;
                    bool mk = rowm || (gx < 5) || (gx > WW - 6);
                    k[j] = respkey(Sxx, Syy, Sxy, mk);
                }
                u32 km = max(max(k[0], k[1]), max(k[2], k[3]));
                #pragma unroll
                for (int off = 1; off < 16; off <<= 1)
                    km = max(km, (u32)__shfl_xor((int)km, off));
                if ((lane & 15) == 0)
                    gmax[((size_t)b << 14) | ((size_t)y << 4) | (u32)(strip * 4 + (lane >> 4))] = km;
            }
            #pragma unroll
            for (int j = 0; j < 4; ++j) {
                a2xx[j] = fadd(fadd(fadd(a1xx[j], fmul(2.0f,pxx[j])),
                               fmul(4.0f,pxx[j+1])), fmul(2.0f,pxx[j+2]));
                a2yy[j] = fadd(fadd(fadd(a1yy[j], fmul(2.0f,pyy[j])),
                               fmul(4.0f,pyy[j+1])), fmul(2.0f,pyy[j+2]));
                a2xy[j] = fadd(fadd(fadd(a1xy[j], fmul(2.0f,pxy[j])),
                               fmul(4.0f,pxy[j+1])), fmul(2.0f,pxy[j+2]));
                a1xx[j] = fadd(fadd(pxx[j], fmul(2.0f,pxx[j+1])), pxx[j+2]);
                a1yy[j] = fadd(fadd(pyy[j], fmul(2.0f,pyy[j+1])), pyy[j+2]);
                a1xy[j] = fadd(fadd(pxy[j], fmul(2.0f,pxy[j+1])), pxy[j+2]);
            }
        }
    }
}

// ---------------------------------------------------------------------------
// Pass B (per batch): bin 16K granule maxes, pick largest bin with
// granule-suffix >= KTOP (sound cutoff), compact qualifying granule ids.
__global__ __launch_bounds__(512) void select_b(const u32* __restrict__ gmax,
                                                u32* __restrict__ glist,
                                                u32* __restrict__ gcount,
                                                u32* __restrict__ cutb,
                                                u32* __restrict__ cnt) {
    __shared__ u32 hist[NBINS];
    __shared__ u32 wsum[8];
    __shared__ u32 s_cut, s_n;
    const int b = blockIdx.x;
    const int tid = threadIdx.x;
    const u32* gm = gmax + ((size_t)b << 14);
    u32 val[32];
    #pragma unroll
    for (int j = 0; j < 8; ++j) {
        uint4 v = ((const uint4*)gm)[tid + j * 512];
        val[j*4+0]=v.x; val[j*4+1]=v.y; val[j*4+2]=v.z; val[j*4+3]=v.w;
    }
    for (int i = tid; i < NBINS; i += 512) hist[i] = 0u;
    if (tid == 0) { s_n = 0u; cnt[b * 16] = 0u; }
    __syncthreads();
    #pragma unroll
    for (int j = 0; j < 32; ++j) atomicAdd(&hist[val[j] >> 20], 1u);
    __syncthreads();
    u32 lv[8], ls = 0;
    #pragma unroll
    for (int i = 0; i < 8; ++i) { lv[i] = hist[tid*8+i]; ls += lv[i]; }
    const int lane = tid & 63, w = tid >> 6;
    u32 v = ls;
    #pragma unroll
    for (int off = 1; off < 64; off <<= 1) {
        u32 t2 = (u32)__shfl_down((int)v, off);
        if (lane + off < 64) v += t2;
    }
    if (lane == 0) wsum[w] = v;
    __syncthreads();
    u32 excl = v - ls;
    #pragma unroll
    for (int i = 0; i < 8; ++i) if (i > w) excl += wsum[i];
    if (excl < KTOP && excl + ls >= KTOP) {       // exactly one thread
        u32 acc = excl;
        #pragma unroll
        for (int i = 7; i >= 0; --i) {
            acc += lv[i];
            if (acc >= KTOP) { s_cut = (u32)(tid*8 + i); break; }
        }
    }
    __syncthreads();
    const u32 cut = s_cut;
    u32* gl = glist + ((size_t)b << 14);
    #pragma unroll
    for (int j = 0; j < 8; ++j)
        #pragma unroll
        for (int kk = 0; kk < 4; ++kk) {
            u32 gv = val[j*4+kk];
            if ((gv >> 20) >= cut) {
                u32 q = atomicAdd(&s_n, 1u);
                gl[q] = (u32)(j*2048 + 4*tid + kk);
            }
        }
    __syncthreads();
    if (tid == 0) { gcount[b] = s_n; cutb[b] = cut; }
}

// ---------------------------------------------------------------------------
// Exact per-pixel recompute: identical _rn expression trees as harris_a.
__device__ __forceinline__ u32 harris_px(const float* __restrict__ p0,
                                         const float* __restrict__ p1,
                                         const float* __restrict__ p2,
                                         int gy, int gx) {
    if (gy < 5 || gy > HH - 6 || gx < 5 || gx > WW - 6) return 0x80000000u;
    float m[5][5];
    #pragma unroll
    for (int r = 0; r < 5; ++r)
        #pragma unroll
        for (int c = 0; c < 5; ++c) {
            size_t o = (size_t)(gy - 2 + r) * WW + (gx - 2 + c);
            m[r][c] = mean3(p0[o], p1[o], p2[o]);
        }
    float pxx[3][3], pyy[3][3], pxy[3][3];
    #pragma unroll
    for (int pr = 0; pr < 3; ++pr) {
        float s[5], ht[3], hb[3];
        #pragma unroll
        for (int c = 0; c < 5; ++c) s[c] = add3(m[pr][c], m[pr+1][c], m[pr+2][c]);
        #pragma unroll
        for (int c = 0; c < 3; ++c) {
            ht[c] = add3(m[pr][c],   m[pr][c+1],   m[pr][c+2]);
            hb[c] = add3(m[pr+2][c], m[pr+2][c+1], m[pr+2][c+2]);
        }
        #pragma unroll
        for (int pc = 0; pc < 3; ++pc) {
            float dx = fsub(s[pc+2], s[pc]);
            float dy = fsub(hb[pc], ht[pc]);
            pxx[pr][pc] = fmul(dx, dx);
            pyy[pr][pc] = fmul(dy, dy);
            pxy[pr][pc] = fmul(dx, dy);
        }
    }
    float Sxx = g9(pxx[0][0],pxx[0][1],pxx[0][2],pxx[1][0],pxx[1][1],pxx[1][2],pxx[2][0],pxx[2][1],pxx[2][2]);
    float Syy = g9(pyy[0][0],pyy[0][1],pyy[0][2],pyy[1][0],pyy[1][1],pyy[1][2],pyy[2][0],pyy[2][1],pyy[2][2]);
    float Sxy = g9(pxy[0][0],pxy[0][1],pxy[0][2],pxy[1][0],pxy[1][1],pxy[1][2],pxy[2][0],pxy[2][1],pxy[2][2]);
    return respkey(Sxx, Syy, Sxy, false);
}

// Pass C: recompute surviving granules; hits staged in 32 KB block LDS,
// ONE global atomicAdd per block on a per-batch padded counter.
// RGRID=64 blocks/batch at 32 KB LDS -> ~4 blocks/CU (vs 2 at 64 KB).
__global__ __launch_bounds__(256) void refine_c(const float* __restrict__ x,
                                                const u32* __restrict__ glist,
                                                const u32* __restrict__ gcount,
                                                const u32* __restrict__ cutb,
                                                u32* __restrict__ cnt,
                                                u64* __restrict__ cand) {
    __shared__ u64 sbuf[LCAP];      // 32 KB staging
    __shared__ u32 s_n, s_base;
    const int b = blockIdx.y;
    const u32 gc  = gcount[b];
    const u32 cut = cutb[b];
    const int tid = threadIdx.x;
    const int wv = tid >> 6, lane = tid & 63;
    if (tid == 0) s_n = 0u;
    __syncthreads();

    const u32 per = (gc + RGRID - 1) / RGRID;    // contiguous chunks
    const u32 i0  = blockIdx.x * per;
    const u32 i1  = min(i0 + per, gc);
    const float* p0 = x + (size_t)b * 3 * HH * WW;
    const float* p1 = p0 + HH * WW;
    const float* p2 = p1 + HH * WW;
    const u32* gl = glist + ((size_t)b << 14);

    for (u32 i = i0 + wv; i < i1; i += 4) {
        u32 gid = gl[i];
        int gy = (int)(gid >> 4);
        int gx = (int)((gid & 15u) << 6) + lane;
        u32 key = harris_px(p0, p1, p2, gy, gx);
        bool pred = (key >> 20) >= cut;
        u64 mball = __ballot(pred);
        if (mball) {
            int first = __ffsll((unsigned long long)mball) - 1;
            u32 base = 0;
            if (lane == first) base = atomicAdd(&s_n, (u32)__popcll(mball));
            base = __shfl(base, first);
            if (pred) {
                u32 q = base + (u32)__popcll(mball & ((1ull << lane) - 1));
                if (q < LCAP) sbuf[q] = ((u64)key << 32) | (u32)~((u32)(gy << 10) | (u32)gx);
            }
        }
    }
    __syncthreads();
    u32 n = min(s_n, (u32)LCAP);
    if (tid == 0) s_base = atomicAdd(&cnt[b * 16], n);   // padded: 1 counter / 64B line
    __syncthreads();
    u32 gb = s_base;
    u64* cb = cand + (size_t)b * CAP;
    for (u32 j = tid; j < n; j += 256) {
        u32 q = gb + j;
        if (q < CAP) cb[q] = sbuf[j];
    }
}

// ---------------------------------------------------------------------------
// Pass D: radix pre-select (shrink n to ~KTOP) + bitonic sort + coords.
__global__ __launch_bounds__(1024) void sort_d(const u32* __restrict__ cnt,
                                               const u64* __restrict__ cand,
                                               float* __restrict__ out) {
    __shared__ u64 s[CAP];                 // 64 KB; head doubles as u32 hist[4096]
    __shared__ u32 wsum[16];
    __shared__ u32 s_cut2, s_n2;
    const int b = blockIdx.x;
    const int tid = threadIdx.x;
    u32 n = cnt[b * 16];
    if (n > CAP) n = CAP;
    const u64* cb = cand + (size_t)b * CAP;

    // Phase 0: histogram of candidate value-bins (top 12 bits of u64 key).
    u32* hs = (u32*)s;                     // first 16 KB of s
    for (int i = tid; i < NBINS; i += 1024) hs[i] = 0u;
    if (tid == 0) { s_n2 = 0u; s_cut2 = 0u; }
    __syncthreads();
    for (u32 i = tid; i < n; i += 1024)
        atomicAdd(&hs[(u32)(cb[i] >> 52)], 1u);
    __syncthreads();

    // Phase 1: pixel-level cutoff c2 = largest bin with suffix >= KTOP.
    {
        u32 lv[4], ls = 0;
        #pragma unroll
        for (int i = 0; i < 4; ++i) { lv[i] = hs[tid*4 + i]; ls += lv[i]; }
        const int lane = tid & 63, w = tid >> 6;   // 16 waves
        u32 v = ls;
        #pragma unroll
        for (int off = 1; off < 64; off <<= 1) {
            u32 t2 = (u32)__shfl_down((int)v, off);
            if (lane + off < 64) v += t2;
        }
        if (lane == 0) wsum[w] = v;
        __syncthreads();
        u32 excl = v - ls;
        #pragma unroll
        for (int i = 0; i < 16; ++i) if (i > w) excl += wsum[i];
        if (excl < KTOP && excl + ls >= KTOP) {    // exactly one thread
            u32 acc = excl;
            #pragma unroll
            for (int i = 3; i >= 0; --i) {
                acc += lv[i];
                if (acc >= KTOP) { s_cut2 = (u32)(tid*4 + i); break; }
            }
        }
    }
    __syncthreads();
    const u32 c2 = s_cut2;
    __syncthreads();                       // hist no longer needed; s reusable

    // Phase 2: gather keys with bin >= c2 (superset of top-KTOP).
    for (u32 i = tid; i < n; i += 1024) {
        u64 k = cb[i];
        if ((u32)(k >> 52) >= c2) {
            u32 q = atomicAdd(&s_n2, 1u);
            s[q] = k;                      // n2 <= n <= CAP always fits
        }
    }
    __syncthreads();
    u32 n2 = s_n2;
    u32 P = 512;
    while (P < n2) P <<= 1;
    for (u32 i = n2 + tid; i < P; i += 1024) s[i] = 0ULL;
    __syncthreads();

    // Phase 3: bitonic sort (descending) + output.
    for (u32 size = 2; size <= P; size <<= 1) {
        for (u32 stride = size >> 1; stride > 0; stride >>= 1) {
            for (u32 t = tid; t < (P >> 1); t += 1024) {
                u32 i = 2 * t - (t & (stride - 1));
                u32 j = i + stride;
                u64 a = s[i], c = s[j];
                bool desc = ((i & size) == 0);
                if (desc ? (a < c) : (a > c)) { s[i] = c; s[j] = a; }
            }
            __syncthreads();
        }
    }
    if (tid < KTOP) {
        u64 k = s[tid];
        u32 idx = ~(u32)k;
        u32 row = idx >> 10, col = idx & 1023;
        float rf = ((float)row * (1.0f / 1024.0f) - 0.5f) * 2.0f;
        float cf = ((float)col * (1.0f / 1024.0f) - 0.5f) * 2.0f;
        rf = fminf(fmaxf(rf, -1.0f), 1.0f);
        cf = fminf(fmaxf(cf, -1.0f), 1.0f);
        float* o = out + ((size_t)b * KTOP + tid) * 2;
        o[0] = rf;
        o[1] = cf;
    }
}

extern "C" void kernel_launch(void* const* d_in, const int* in_sizes, int n_in,
                              void* d_out, int out_size, void* d_ws, size_t ws_size,
                              hipStream_t stream) {
    const float* x = (const float*)d_in[0];
    float* out = (float*)d_out;
    char* ws = (char*)d_ws;

    // ws layout (bytes):
    //   [0, 1MB)       gmax   u32[16*16384]
    //   [1MB, 2MB)     glist  u32[16*16384]
    //   @2MB           gcount u32[16]
    //   @2MB+64        cutb   u32[16]
    //   @2MB+128       cnt    u32[16*16]   (padded: one counter per 64B line)
    //   @2MB+2048      cand   u64[16*8192] (1MB)
    u32* gmax   = (u32*)ws;
    u32* glist  = (u32*)(ws + (1u << 20));
    u32* gcount = (u32*)(ws + (2u << 20));
    u32* cutb   = (u32*)(ws + (2u << 20) + 64);
    u32* cnt    = (u32*)(ws + (2u << 20) + 128);
    u64* cand   = (u64*)(ws + (2u << 20) + 2048);

    hipLaunchKernelGGL(harris_a, dim3(64, NB), dim3(256), 0, stream, x, gmax);
    hipLaunchKernelGGL(select_b, dim3(NB), dim3(512), 0, stream, gmax, glist, gcount, cutb, cnt);
    hipLaunchKernelGGL(refine_c, dim3(RGRID, NB), dim3(256), 0, stream, x, glist, gcount, cutb, cnt, cand);
    hipLaunchKernelGGL(sort_d, dim3(NB), dim3(1024), 0, stream, cnt, cand, out);
}